// Round 1
// baseline (465.323 us; speedup 1.0000x reference)
//
#include <hip/hip_runtime.h>

// Problem constants (from reference): texture [1024,1024,17] f32, uv [N,2] f32.
// Outputs flat: values (N*16) || homogeneous (N*1) || vnn (N*17).
#define TEX_H 1024
#define TEX_W 1024
#define TEX_C 17

__global__ __launch_bounds__(256) void slice_texture_kernel(
    const float* __restrict__ tex,
    const float* __restrict__ uv,
    float* __restrict__ out,
    int n)
{
    int i = blockIdx.x * blockDim.x + threadIdx.x;
    if (i >= n) return;

    // Coalesced 8B/lane uv load.
    float2 p = ((const float2*)uv)[i];

    float x = p.x * (float)(TEX_W - 1);
    float y = p.y * (float)(TEX_H - 1);
    float x0f = fminf(fmaxf(floorf(x), 0.0f), (float)(TEX_W - 2));
    float y0f = fminf(fmaxf(floorf(y), 0.0f), (float)(TEX_H - 2));
    int x0 = (int)x0f;
    int y0 = (int)y0f;
    float fx = x - x0f;
    float fy = y - y0f;
    float gx = 1.0f - fx;
    float gy = 1.0f - fy;

    // Row pointers: t00||t01 are 2*17 contiguous floats; same for t10||t11.
    const float* r0 = tex + ((size_t)y0 * TEX_W + (size_t)x0) * TEX_C;
    const float* r1 = r0 + (size_t)TEX_W * TEX_C;

    float vnn[TEX_C];
#pragma unroll
    for (int c = 0; c < TEX_C; ++c) {
        float t00 = r0[c];
        float t01 = r0[c + TEX_C];
        float t10 = r1[c];
        float t11 = r1[c + TEX_C];
        float top = t00 * gx + t01 * fx;
        float bot = t10 * gx + t11 * fx;
        vnn[c] = top * gy + bot * fy;
    }

    float h = vnn[16];
    float inv = 1.0f / (h + 1e-5f);   // exact div once; 2% absmax threshold makes rounding moot

    // values: rows of 16 floats = 64B, aligned -> 4x float4 stores.
    float4* vrow = (float4*)(out + (size_t)i * 16);
#pragma unroll
    for (int q = 0; q < 4; ++q) {
        float4 v;
        v.x = vnn[q * 4 + 0] * inv;
        v.y = vnn[q * 4 + 1] * inv;
        v.z = vnn[q * 4 + 2] * inv;
        v.w = vnn[q * 4 + 3] * inv;
        vrow[q] = v;
    }

    // homogeneous: perfectly coalesced scalar store.
    out[(size_t)n * 16 + i] = h;

    // vnn: rows of 17 floats (68B, 4B-aligned only) -> scalar stores for safety.
    float* vout = out + (size_t)n * 17 + (size_t)i * 17;
#pragma unroll
    for (int c = 0; c < TEX_C; ++c) {
        vout[c] = vnn[c];
    }
}

extern "C" void kernel_launch(void* const* d_in, const int* in_sizes, int n_in,
                              void* d_out, int out_size, void* d_ws, size_t ws_size,
                              hipStream_t stream) {
    const float* tex = (const float*)d_in[0];
    const float* uv  = (const float*)d_in[1];
    float* out = (float*)d_out;
    int n = in_sizes[1] / 2;  // N points

    const int block = 256;
    const int grid = (n + block - 1) / block;
    slice_texture_kernel<<<grid, block, 0, stream>>>(tex, uv, out, n);
}